// Round 2
// baseline (986.183 us; speedup 1.0000x reference)
//
#include <hip/hip_runtime.h>
#include <stdint.h>

#define E_ 8
#define D_ 1024
#define F_ 4096
#define NTOK 8192
#define NASSIGN 16384
#define CAP 17408   // 16384 + 8*128 worst-case padding, multiple of 128

typedef __attribute__((ext_vector_type(8))) short short8;
typedef __attribute__((ext_vector_type(8))) __bf16 bf16x8;
typedef __attribute__((ext_vector_type(4))) float f32x4;

__device__ __forceinline__ ushort f2bf(float f) {
  uint32_t u = __float_as_uint(f);
  uint32_t r = (u + 0x7fffu + ((u >> 16) & 1u)) >> 16;
  return (ushort)r;
}

__device__ __forceinline__ f32x4 mfma16(short8 a, short8 b, f32x4 c) {
  return __builtin_amdgcn_mfma_f32_16x16x32_bf16(
      __builtin_bit_cast(bf16x8, a), __builtin_bit_cast(bf16x8, b), c, 0, 0, 0);
}

// ---------------- cast x (fp32) -> xb (bf16) ----------------
__global__ __launch_bounds__(256) void cast_x_kernel(const float* __restrict__ x,
                                                     ushort* __restrict__ xb) {
  size_t idx = (size_t)blockIdx.x * 256 + threadIdx.x;
  const float* s = x + idx * 8;
  float4 a = *(const float4*)s;
  float4 b = *(const float4*)(s + 4);
  ushort o[8] = {f2bf(a.x), f2bf(a.y), f2bf(a.z), f2bf(a.w),
                 f2bf(b.x), f2bf(b.y), f2bf(b.z), f2bf(b.w)};
  *(uint4*)(xb + idx * 8) = *(const uint4*)o;
}

// ---------------- router: one wave per token, all fp32 ----------------
__global__ __launch_bounds__(256) void router_kernel(
    const float* __restrict__ x, const float* __restrict__ Wr,
    int* __restrict__ cnt, float* __restrict__ imp, float* __restrict__ z2,
    int* __restrict__ tke, float* __restrict__ tkw)
{
  __shared__ float sWr[E_ * D_];
  __shared__ float bImp[E_];
  __shared__ float bZ2;
  __shared__ int bCnt[E_];
  int tid = threadIdx.x;
  for (int i = 0; i < 4; i++) {
    int d = tid + i * 256;
    float4 v0 = *(const float4*)(Wr + (size_t)d * E_);
    float4 v1 = *(const float4*)(Wr + (size_t)d * E_ + 4);
    sWr[0 * D_ + d] = v0.x; sWr[1 * D_ + d] = v0.y;
    sWr[2 * D_ + d] = v0.z; sWr[3 * D_ + d] = v0.w;
    sWr[4 * D_ + d] = v1.x; sWr[5 * D_ + d] = v1.y;
    sWr[6 * D_ + d] = v1.z; sWr[7 * D_ + d] = v1.w;
  }
  if (tid < E_) { bImp[tid] = 0.f; bCnt[tid] = 0; }
  if (tid == E_) bZ2 = 0.f;
  __syncthreads();

  int wave = tid >> 6, lane = tid & 63;
  int t = blockIdx.x * 4 + wave;
  const float* xr = x + (size_t)t * D_;
  float part[E_];
  for (int e = 0; e < E_; e++) part[e] = 0.f;
  for (int i = 0; i < 4; i++) {
    int d0 = i * 256 + lane * 4;
    float4 xv = *(const float4*)(xr + d0);
    for (int e = 0; e < E_; e++)
      part[e] += xv.x * sWr[e * D_ + d0] + xv.y * sWr[e * D_ + d0 + 1] +
                 xv.z * sWr[e * D_ + d0 + 2] + xv.w * sWr[e * D_ + d0 + 3];
  }
  for (int sh = 32; sh >= 1; sh >>= 1)
    for (int e = 0; e < E_; e++)
      part[e] += __shfl_xor(part[e], sh, 64);

  // top-2, JAX tie semantics (first index wins)
  float v1 = part[0]; int i1 = 0;
  for (int e = 1; e < E_; e++) if (part[e] > v1) { v1 = part[e]; i1 = e; }
  float v2 = -3.4e38f; int i2 = 0;
  for (int e = 0; e < E_; e++) if (e != i1 && part[e] > v2) { v2 = part[e]; i2 = e; }
  float w1f = 1.f / (1.f + __expf(v2 - v1));
  float w2f = 1.f - w1f;

  float s = 0.f;
  float pr[E_];
  for (int e = 0; e < E_; e++) { float ex = __expf(part[e] - v1); pr[e] = ex; s += ex; }
  float inv = 1.f / s;
  float z = v1 + __logf(s);

  if (lane == 0) {
    tke[2 * t] = i1; tke[2 * t + 1] = i2;
    tkw[2 * t] = w1f; tkw[2 * t + 1] = w2f;
    for (int e = 0; e < E_; e++) atomicAdd(&bImp[e], pr[e] * inv);
    atomicAdd(&bZ2, z * z);
    atomicAdd(&bCnt[i1], 1);
    atomicAdd(&bCnt[i2], 1);
  }
  __syncthreads();
  if (tid < E_) { atomicAdd(&imp[tid], bImp[tid]); atomicAdd(&cnt[tid], bCnt[tid]); }
  if (tid == E_) atomicAdd(z2, bZ2);
}

// ---------------- finalize: offsets + tail outputs (all fp32) ----------------
__global__ void finalize_kernel(const int* __restrict__ cnt, const float* __restrict__ imp,
                                const float* __restrict__ z2, int* __restrict__ off,
                                float* __restrict__ tail)
{
  if (threadIdx.x == 0 && blockIdx.x == 0) {
    int o = 0;
    for (int e = 0; e < E_; e++) { off[e] = o; o += ((cnt[e] + 127) & ~127); }
    off[E_] = o;
    for (int e = 0; e < E_; e++) tail[e] = (float)cnt[e];
    for (int e = 0; e < E_; e++) tail[E_ + e] = (float)cnt[e] / (float)NASSIGN;
    float sum2 = 0.f;
    for (int e = 0; e < E_; e++) { float p = imp[e] / (float)NTOK; sum2 += p * p; }
    float lb = 8.f * sum2 * 0.01f;
    float zl = (z2[0] / (float)NTOK) * 0.001f;
    tail[2 * E_] = lb + zl;
  }
}

// ---------------- scatter tokens into expert-sorted rows ----------------
__global__ __launch_bounds__(256) void scatter_kernel(
    const int* __restrict__ tke, const int* __restrict__ off, int* __restrict__ fill,
    int* __restrict__ rowtok, int* __restrict__ tpos)
{
  int t = blockIdx.x * 256 + threadIdx.x;
  if (t >= NTOK) return;
  for (int k = 0; k < 2; k++) {
    int e = tke[2 * t + k];
    int pos = off[e] + atomicAdd(&fill[e], 1);
    rowtok[pos] = t;
    tpos[2 * t + k] = pos;
  }
}

// ------- transpose+cast: dst(bf16)[z][c][r] = src(fp32)[z][r][c] -------
__global__ __launch_bounds__(256) void transpose_cast_kernel(
    const float* __restrict__ src, ushort* __restrict__ dst, int R, int C)
{
  __shared__ float tile[64][68];
  const float* s = src + (size_t)blockIdx.z * R * C;
  ushort* d = dst + (size_t)blockIdx.z * R * C;
  int c0 = blockIdx.x * 64, r0 = blockIdx.y * 64;
  int tid = threadIdx.x;
  {
    int row = tid >> 2;
    int col4 = (tid & 3) * 16;
    const float* sp = s + (size_t)(r0 + row) * C + c0 + col4;
    for (int q = 0; q < 4; q++)
      *(float4*)&tile[row][col4 + q * 4] = *(const float4*)(sp + q * 4);
  }
  __syncthreads();
  int tr = tid >> 3;
  int tc = (tid & 7) * 8;
  for (int i = 0; i < 2; i++) {
    int cr = tr + i * 32;
    ushort tmp[8];
    for (int j = 0; j < 8; j++) tmp[j] = f2bf(tile[tc + j][cr]);
    *(uint4*)(d + (size_t)(c0 + cr) * R + r0 + tc) = *(const uint4*)tmp;
  }
}

// ---------------- GEMM1: H(bf16) = relu(gather(X) @ W1[e] + b1[e]) ----------------
template<bool XB, bool BT>
__global__ __launch_bounds__(256) void gemm1_kernel(
    const float* __restrict__ x, const ushort* __restrict__ xb,
    const ushort* __restrict__ W1bt, const float* __restrict__ W1nat,
    const float* __restrict__ b1, const int* __restrict__ rowtok,
    const int* __restrict__ off, ushort* __restrict__ H, int chunk_base)
{
  __shared__ ushort As[128 * 72];
  __shared__ ushort Bs[128 * 72];
  int row0 = chunk_base + blockIdx.x * 128;
  int total = off[E_];
  if (row0 >= total) return;
  int e = 0;
  while (e < E_ - 1 && off[e + 1] <= row0) e++;
  int f0 = blockIdx.y * 128;
  int tid = threadIdx.x;
  int wave = tid >> 6, lane = tid & 63;
  int wm = wave & 1, wn = wave >> 1;
  int l15 = lane & 15, quad = lane >> 4;

  int r = tid >> 1, h = tid & 1;
  int tokA = rowtok[row0 + r];
  size_t aoff = ((tokA >= 0) ? (size_t)tokA * D_ : 0) + h * 32;

  f32x4 acc[4][4];
  f32x4 zz = {0.f, 0.f, 0.f, 0.f};
  for (int i = 0; i < 4; i++) for (int j = 0; j < 4; j++) acc[i][j] = zz;

  for (int k0 = 0; k0 < D_; k0 += 64) {
    for (int q = 0; q < 4; q++) {
      uint4 v;
      if (tokA >= 0) {
        if (XB) {
          v = *(const uint4*)(xb + aoff + k0 + q * 8);
        } else {
          float4 fa = *(const float4*)(x + aoff + k0 + q * 8);
          float4 fb = *(const float4*)(x + aoff + k0 + q * 8 + 4);
          ushort t8[8] = {f2bf(fa.x), f2bf(fa.y), f2bf(fa.z), f2bf(fa.w),
                          f2bf(fb.x), f2bf(fb.y), f2bf(fb.z), f2bf(fb.w)};
          v = *(const uint4*)t8;
        }
      } else v = make_uint4(0u, 0u, 0u, 0u);
      *(uint4*)&As[r * 72 + h * 32 + q * 8] = v;
    }
    if (BT) {
      const ushort* bs = W1bt + ((size_t)e * F_ + f0 + r) * D_ + k0 + h * 32;
      for (int q = 0; q < 4; q++)
        *(uint4*)&Bs[r * 72 + h * 32 + q * 8] = *(const uint4*)(bs + q * 8);
    } else {
      for (int i = 0; i < 8; i++) {
        int c = tid + i * 256;
        int kk = c >> 5;
        int n4 = (c & 31) * 4;
        float4 v = *(const float4*)(W1nat + (size_t)e * D_ * F_ +
                                    (size_t)(k0 + kk) * F_ + f0 + n4);
        Bs[(n4 + 0) * 72 + kk] = f2bf(v.x);
        Bs[(n4 + 1) * 72 + kk] = f2bf(v.y);
        Bs[(n4 + 2) * 72 + kk] = f2bf(v.z);
        Bs[(n4 + 3) * 72 + kk] = f2bf(v.w);
      }
    }
    __syncthreads();
    for (int s = 0; s < 2; s++) {
      int kc = s * 32 + quad * 8;
      short8 a[4], b[4];
      for (int i = 0; i < 4; i++)
        a[i] = *(const short8*)&As[(wm * 64 + i * 16 + l15) * 72 + kc];
      for (int j = 0; j < 4; j++)
        b[j] = *(const short8*)&Bs[(wn * 64 + j * 16 + l15) * 72 + kc];
      for (int i = 0; i < 4; i++)
        for (int j = 0; j < 4; j++)
          acc[i][j] = mfma16(a[i], b[j], acc[i][j]);
    }
    __syncthreads();
  }

  float bv[4];
  for (int j = 0; j < 4; j++)
    bv[j] = b1[e * F_ + f0 + wn * 64 + j * 16 + l15];
  ushort* Hb = H + (size_t)(row0 - chunk_base) * F_;
  for (int i = 0; i < 4; i++) {
    int mrow = wm * 64 + i * 16 + quad * 4;
    for (int rg = 0; rg < 4; rg++) {
      ushort* dst = Hb + (size_t)(mrow + rg) * F_ + f0;
      for (int j = 0; j < 4; j++) {
        float vv = acc[i][j][rg] + bv[j];
        vv = vv > 0.f ? vv : 0.f;
        dst[wn * 64 + j * 16 + l15] = f2bf(vv);
      }
    }
  }
}

// ---------------- GEMM2: Ya = H @ W2[e] ----------------
template<bool BT, bool YF32>
__global__ __launch_bounds__(256) void gemm2_kernel(
    const ushort* __restrict__ H, const ushort* __restrict__ W2bt,
    const float* __restrict__ W2nat, const int* __restrict__ off,
    void* __restrict__ Ya, int chunk_base)
{
  __shared__ ushort As[128 * 72];
  __shared__ ushort Bs[128 * 72];
  int row0 = chunk_base + blockIdx.x * 128;
  int total = off[E_];
  if (row0 >= total) return;
  int e = 0;
  while (e < E_ - 1 && off[e + 1] <= row0) e++;
  int d0 = blockIdx.y * 128;
  int tid = threadIdx.x;
  int wave = tid >> 6, lane = tid & 63;
  int wm = wave & 1, wn = wave >> 1;
  int l15 = lane & 15, quad = lane >> 4;

  int r = tid >> 1, h = tid & 1;
  const ushort* aSrc = H + (size_t)(blockIdx.x * 128 + r) * F_ + h * 32;

  f32x4 acc[4][4];
  f32x4 zz = {0.f, 0.f, 0.f, 0.f};
  for (int i = 0; i < 4; i++) for (int j = 0; j < 4; j++) acc[i][j] = zz;

  for (int k0 = 0; k0 < F_; k0 += 64) {
    for (int q = 0; q < 4; q++)
      *(uint4*)&As[r * 72 + h * 32 + q * 8] = *(const uint4*)(aSrc + k0 + q * 8);
    if (BT) {
      const ushort* bs = W2bt + ((size_t)e * D_ + d0 + r) * F_ + k0 + h * 32;
      for (int q = 0; q < 4; q++)
        *(uint4*)&Bs[r * 72 + h * 32 + q * 8] = *(const uint4*)(bs + q * 8);
    } else {
      for (int i = 0; i < 8; i++) {
        int c = tid + i * 256;
        int kk = c >> 5;
        int n4 = (c & 31) * 4;
        float4 v = *(const float4*)(W2nat + (size_t)e * F_ * D_ +
                                    (size_t)(k0 + kk) * D_ + d0 + n4);
        Bs[(n4 + 0) * 72 + kk] = f2bf(v.x);
        Bs[(n4 + 1) * 72 + kk] = f2bf(v.y);
        Bs[(n4 + 2) * 72 + kk] = f2bf(v.z);
        Bs[(n4 + 3) * 72 + kk] = f2bf(v.w);
      }
    }
    __syncthreads();
    for (int s = 0; s < 2; s++) {
      int kc = s * 32 + quad * 8;
      short8 a[4], b[4];
      for (int i = 0; i < 4; i++)
        a[i] = *(const short8*)&As[(wm * 64 + i * 16 + l15) * 72 + kc];
      for (int j = 0; j < 4; j++)
        b[j] = *(const short8*)&Bs[(wn * 64 + j * 16 + l15) * 72 + kc];
      for (int i = 0; i < 4; i++)
        for (int j = 0; j < 4; j++)
          acc[i][j] = mfma16(a[i], b[j], acc[i][j]);
    }
    __syncthreads();
  }

  for (int i = 0; i < 4; i++) {
    int mrow = wm * 64 + i * 16 + quad * 4;
    for (int rg = 0; rg < 4; rg++) {
      size_t base = (size_t)(row0 + mrow + rg) * D_ + d0;
      for (int j = 0; j < 4; j++) {
        int cc = wn * 64 + j * 16 + l15;
        if (YF32) ((float*)Ya)[base + cc] = acc[i][j][rg];
        else ((ushort*)Ya)[base + cc] = f2bf(acc[i][j][rg]);
      }
    }
  }
}

// -------- combine: y[t] = w0*(Ya[p0]+b2[e0]) + w1*(Ya[p1]+b2[e1]) --------
template<bool YF32>
__global__ __launch_bounds__(256) void combine_kernel(
    const void* __restrict__ Ya, const float* __restrict__ b2,
    const int* __restrict__ tpos, const int* __restrict__ tke,
    const float* __restrict__ tkw, float* __restrict__ y)
{
  int t = blockIdx.x;
  int c = threadIdx.x * 4;
  int p0 = tpos[2 * t], p1 = tpos[2 * t + 1];
  int e0 = tke[2 * t], e1 = tke[2 * t + 1];
  float w0 = tkw[2 * t], w1 = tkw[2 * t + 1];
  float a0[4], a1[4];
  if (YF32) {
    float4 va = *(const float4*)((const float*)Ya + (size_t)p0 * D_ + c);
    float4 vb = *(const float4*)((const float*)Ya + (size_t)p1 * D_ + c);
    a0[0] = va.x; a0[1] = va.y; a0[2] = va.z; a0[3] = va.w;
    a1[0] = vb.x; a1[1] = vb.y; a1[2] = vb.z; a1[3] = vb.w;
  } else {
    uint2 ua = *(const uint2*)((const ushort*)Ya + (size_t)p0 * D_ + c);
    uint2 ub = *(const uint2*)((const ushort*)Ya + (size_t)p1 * D_ + c);
    const ushort* pa = (const ushort*)&ua;
    const ushort* pb = (const ushort*)&ub;
    for (int q = 0; q < 4; q++) {
      a0[q] = __uint_as_float(((uint32_t)pa[q]) << 16);
      a1[q] = __uint_as_float(((uint32_t)pb[q]) << 16);
    }
  }
  float4 vb0 = *(const float4*)(b2 + (size_t)e0 * D_ + c);
  float4 vb1 = *(const float4*)(b2 + (size_t)e1 * D_ + c);
  float4 o;
  o.x = w0 * (a0[0] + vb0.x) + w1 * (a1[0] + vb1.x);
  o.y = w0 * (a0[1] + vb0.y) + w1 * (a1[1] + vb1.y);
  o.z = w0 * (a0[2] + vb0.z) + w1 * (a1[2] + vb1.z);
  o.w = w0 * (a0[3] + vb0.w) + w1 * (a1[3] + vb1.w);
  *(float4*)(y + (size_t)t * D_ + c) = o;
}

extern "C" void kernel_launch(void* const* d_in, const int* in_sizes, int n_in,
                              void* d_out, int out_size, void* d_ws, size_t ws_size,
                              hipStream_t stream) {
  (void)in_sizes; (void)n_in; (void)out_size;
  const float* x  = (const float*)d_in[0];
  const float* Wr = (const float*)d_in[1];
  const float* W1 = (const float*)d_in[2];
  const float* b1 = (const float*)d_in[3];
  const float* W2 = (const float*)d_in[4];
  const float* b2 = (const float*)d_in[5];
  float* out = (float*)d_out;

  char* ws = (char*)d_ws;
  int*   cnt    = (int*)(ws + 0);
  int*   fill   = (int*)(ws + 32);
  float* imp    = (float*)(ws + 64);
  float* z2     = (float*)(ws + 96);
  int*   off    = (int*)(ws + 128);
  int*   tke    = (int*)(ws + 256);
  float* tkw    = (float*)(ws + 256 + 65536);
  int*   tpos   = (int*)(ws + 256 + 2 * 65536);
  int*   rowtok = (int*)(ws + 256 + 3 * 65536);
  size_t p = 256 + 3 * 65536 + (size_t)CAP * 4;
  p = (p + 4095) & ~(size_t)4095;

  const size_t XB_SZ = (size_t)NTOK * D_ * 2;          // 16.8 MB
  const size_t YA32  = (size_t)CAP * D_ * 4;           // 71.3 MB
  const size_t YA16  = (size_t)CAP * D_ * 2;           // 35.7 MB
  const size_t WT    = (size_t)E_ * D_ * F_ * 2;       // 67.1 MB
  const size_t HROW  = (size_t)F_ * 2;
  const size_t MINH  = 128 * HROW;                     // 1 MB

  bool xb_on = true, ya32 = true;
  if (ws_size < p + XB_SZ + YA32 + MINH) {
    ya32 = false;
    if (ws_size < p + XB_SZ + YA16 + MINH) xb_on = false;
  }
  ushort* xb = nullptr;
  if (xb_on) { xb = (ushort*)(ws + p); p += XB_SZ; }
  void* Ya = (void*)(ws + p);
  p += ya32 ? YA32 : YA16;

  bool w1t_on = false, w2t_on = false;
  ushort* W1bt = nullptr; ushort* W2bt = nullptr;
  if (ws_size >= p + WT + MINH) { w1t_on = true; W1bt = (ushort*)(ws + p); p += WT; }
  if (ws_size >= p + WT + MINH) { w2t_on = true; W2bt = (ushort*)(ws + p); p += WT; }

  size_t hav = ws_size > p ? ws_size - p : 0;
  long long chl = (long long)(hav / HROW);
  int CH = (int)(chl & ~127LL);
  if (CH < 128) CH = 128;
  if (CH > CAP) CH = CAP;
  ushort* Hbuf = (ushort*)(ws + p);
  int nchunks = (CAP + CH - 1) / CH;

  hipMemsetAsync(ws, 0, 128, stream);
  hipMemsetAsync(rowtok, 0xFF, (size_t)CAP * 4, stream);
  if (xb_on)
    cast_x_kernel<<<(NTOK * D_ / 8) / 256, 256, 0, stream>>>(x, xb);
  router_kernel<<<NTOK / 4, 256, 0, stream>>>(x, Wr, cnt, imp, z2, tke, tkw);
  finalize_kernel<<<1, 64, 0, stream>>>(cnt, imp, z2, off, out + (size_t)NTOK * D_);
  scatter_kernel<<<NTOK / 256, 256, 0, stream>>>(tke, off, fill, rowtok, tpos);
  if (w1t_on)
    transpose_cast_kernel<<<dim3(F_ / 64, D_ / 64, E_), 256, 0, stream>>>(W1, W1bt, D_, F_);
  if (w2t_on)
    transpose_cast_kernel<<<dim3(D_ / 64, F_ / 64, E_), 256, 0, stream>>>(W2, W2bt, F_, D_);

  for (int c = 0; c < nchunks; c++) {
    int cb = c * CH;
    dim3 g1(CH / 128, F_ / 128), g2(CH / 128, D_ / 128);
    if (xb_on) {
      if (w1t_on) gemm1_kernel<true, true><<<g1, 256, 0, stream>>>(x, xb, W1bt, W1, b1, rowtok, off, Hbuf, cb);
      else        gemm1_kernel<true, false><<<g1, 256, 0, stream>>>(x, xb, W1bt, W1, b1, rowtok, off, Hbuf, cb);
    } else {
      if (w1t_on) gemm1_kernel<false, true><<<g1, 256, 0, stream>>>(x, xb, W1bt, W1, b1, rowtok, off, Hbuf, cb);
      else        gemm1_kernel<false, false><<<g1, 256, 0, stream>>>(x, xb, W1bt, W1, b1, rowtok, off, Hbuf, cb);
    }
    if (ya32) {
      if (w2t_on) gemm2_kernel<true, true><<<g2, 256, 0, stream>>>(Hbuf, W2bt, W2, off, Ya, cb);
      else        gemm2_kernel<false, true><<<g2, 256, 0, stream>>>(Hbuf, W2bt, W2, off, Ya, cb);
    } else {
      if (w2t_on) gemm2_kernel<true, false><<<g2, 256, 0, stream>>>(Hbuf, W2bt, W2, off, Ya, cb);
      else        gemm2_kernel<false, false><<<g2, 256, 0, stream>>>(Hbuf, W2bt, W2, off, Ya, cb);
    }
  }
  if (ya32) combine_kernel<true><<<NTOK, 256, 0, stream>>>(Ya, b2, tpos, tke, tkw, out);
  else      combine_kernel<false><<<NTOK, 256, 0, stream>>>(Ya, b2, tpos, tke, tkw, out);
}

// Round 3
// 873.135 us; speedup vs baseline: 1.1295x; 1.1295x over previous
//
#include <hip/hip_runtime.h>
#include <stdint.h>

#define E_ 8
#define D_ 1024
#define F_ 4096
#define NTOK 8192
#define NASSIGN 16384
#define CAP 17408   // 16384 + 8*128 worst-case padding, multiple of 128

typedef __attribute__((ext_vector_type(8))) short short8;
typedef __attribute__((ext_vector_type(8))) __bf16 bf16x8;
typedef __attribute__((ext_vector_type(4))) float f32x4;

__device__ __forceinline__ ushort f2bf(float f) {
  uint32_t u = __float_as_uint(f);
  uint32_t r = (u + 0x7fffu + ((u >> 16) & 1u)) >> 16;
  return (ushort)r;
}

__device__ __forceinline__ f32x4 mfma16(short8 a, short8 b, f32x4 c) {
  return __builtin_amdgcn_mfma_f32_16x16x32_bf16(
      __builtin_bit_cast(bf16x8, a), __builtin_bit_cast(bf16x8, b), c, 0, 0, 0);
}

// async global->LDS, 16B per lane. LDS dest is wave-uniform base + lane*16.
__device__ __forceinline__ void gld16(const ushort* g, ushort* l) {
  __builtin_amdgcn_global_load_lds(
      (const __attribute__((address_space(1))) unsigned int*)(const void*)g,
      (__attribute__((address_space(3))) unsigned int*)(void*)l, 16, 0, 0);
}

// ---------------- router: one wave per token, all fp32; fused x->bf16 cast ----------------
__global__ __launch_bounds__(256) void router_kernel(
    const float* __restrict__ x, const float* __restrict__ Wr,
    int* __restrict__ cnt, float* __restrict__ imp, float* __restrict__ z2,
    int* __restrict__ tke, float* __restrict__ tkw, ushort* __restrict__ xb)
{
  __shared__ float sWr[E_ * D_];
  __shared__ float bImp[E_];
  __shared__ float bZ2;
  __shared__ int bCnt[E_];
  int tid = threadIdx.x;
  for (int i = 0; i < 4; i++) {
    int d = tid + i * 256;
    float4 v0 = *(const float4*)(Wr + (size_t)d * E_);
    float4 v1 = *(const float4*)(Wr + (size_t)d * E_ + 4);
    sWr[0 * D_ + d] = v0.x; sWr[1 * D_ + d] = v0.y;
    sWr[2 * D_ + d] = v0.z; sWr[3 * D_ + d] = v0.w;
    sWr[4 * D_ + d] = v1.x; sWr[5 * D_ + d] = v1.y;
    sWr[6 * D_ + d] = v1.z; sWr[7 * D_ + d] = v1.w;
  }
  if (tid < E_) { bImp[tid] = 0.f; bCnt[tid] = 0; }
  if (tid == E_) bZ2 = 0.f;
  __syncthreads();

  int wave = tid >> 6, lane = tid & 63;
  int t = blockIdx.x * 4 + wave;
  const float* xr = x + (size_t)t * D_;
  float part[E_];
  for (int e = 0; e < E_; e++) part[e] = 0.f;
  for (int i = 0; i < 4; i++) {
    int d0 = i * 256 + lane * 4;
    float4 xv = *(const float4*)(xr + d0);
    if (xb) {
      ushort o[4] = {f2bf(xv.x), f2bf(xv.y), f2bf(xv.z), f2bf(xv.w)};
      *(uint2*)(xb + (size_t)t * D_ + d0) = *(const uint2*)o;
    }
    for (int e = 0; e < E_; e++)
      part[e] += xv.x * sWr[e * D_ + d0] + xv.y * sWr[e * D_ + d0 + 1] +
                 xv.z * sWr[e * D_ + d0 + 2] + xv.w * sWr[e * D_ + d0 + 3];
  }
  for (int sh = 32; sh >= 1; sh >>= 1)
    for (int e = 0; e < E_; e++)
      part[e] += __shfl_xor(part[e], sh, 64);

  // top-2, JAX tie semantics (first index wins)
  float v1 = part[0]; int i1 = 0;
  for (int e = 1; e < E_; e++) if (part[e] > v1) { v1 = part[e]; i1 = e; }
  float v2 = -3.4e38f; int i2 = 0;
  for (int e = 0; e < E_; e++) if (e != i1 && part[e] > v2) { v2 = part[e]; i2 = e; }
  float w1f = 1.f / (1.f + __expf(v2 - v1));
  float w2f = 1.f - w1f;

  float s = 0.f;
  float pr[E_];
  for (int e = 0; e < E_; e++) { float ex = __expf(part[e] - v1); pr[e] = ex; s += ex; }
  float inv = 1.f / s;
  float z = v1 + __logf(s);

  if (lane == 0) {
    tke[2 * t] = i1; tke[2 * t + 1] = i2;
    tkw[2 * t] = w1f; tkw[2 * t + 1] = w2f;
    for (int e = 0; e < E_; e++) atomicAdd(&bImp[e], pr[e] * inv);
    atomicAdd(&bZ2, z * z);
    atomicAdd(&bCnt[i1], 1);
    atomicAdd(&bCnt[i2], 1);
  }
  __syncthreads();
  if (tid < E_) { atomicAdd(&imp[tid], bImp[tid]); atomicAdd(&cnt[tid], bCnt[tid]); }
  if (tid == E_) atomicAdd(z2, bZ2);
}

// ---------------- finalize: offsets + tail outputs (all fp32) ----------------
__global__ void finalize_kernel(const int* __restrict__ cnt, const float* __restrict__ imp,
                                const float* __restrict__ z2, int* __restrict__ off,
                                float* __restrict__ tail)
{
  if (threadIdx.x == 0 && blockIdx.x == 0) {
    int o = 0;
    for (int e = 0; e < E_; e++) { off[e] = o; o += ((cnt[e] + 127) & ~127); }
    off[E_] = o;
    for (int e = 0; e < E_; e++) tail[e] = (float)cnt[e];
    for (int e = 0; e < E_; e++) tail[E_ + e] = (float)cnt[e] / (float)NASSIGN;
    float sum2 = 0.f;
    for (int e = 0; e < E_; e++) { float p = imp[e] / (float)NTOK; sum2 += p * p; }
    float lb = 8.f * sum2 * 0.01f;
    float zl = (z2[0] / (float)NTOK) * 0.001f;
    tail[2 * E_] = lb + zl;
  }
}

// ------- scatter with LDS aggregation: 256 global atomics instead of 16384 -------
__global__ __launch_bounds__(256) void scatter_kernel(
    const int* __restrict__ tke, const int* __restrict__ off, int* __restrict__ fill,
    int* __restrict__ rowtok, int* __restrict__ tpos)
{
  __shared__ int lcnt[E_], lbase[E_];
  int tid = threadIdx.x;
  if (tid < E_) lcnt[tid] = 0;
  __syncthreads();
  int t = blockIdx.x * 256 + tid;
  int e0 = tke[2 * t], e1 = tke[2 * t + 1];
  int r0 = atomicAdd(&lcnt[e0], 1);
  int r1 = atomicAdd(&lcnt[e1], 1);
  __syncthreads();
  if (tid < E_) lbase[tid] = atomicAdd(&fill[tid], lcnt[tid]);
  __syncthreads();
  int p0 = off[e0] + lbase[e0] + r0;
  int p1 = off[e1] + lbase[e1] + r1;
  rowtok[p0] = t; rowtok[p1] = t;
  tpos[2 * t] = p0; tpos[2 * t + 1] = p1;
}

// ------- transpose+cast: dst(bf16)[z][c][r] = src(fp32)[z][r][c]; tile is [c][r] -------
__global__ __launch_bounds__(256) void transpose_cast_kernel(
    const float* __restrict__ src, ushort* __restrict__ dst, int R, int C)
{
  __shared__ float tile[64][68];   // [c-idx][r-idx], ld=68 (+4 pad)
  const float* s = src + (size_t)blockIdx.z * R * C;
  ushort* d = dst + (size_t)blockIdx.z * R * C;
  int c0 = blockIdx.x * 64, r0 = blockIdx.y * 64;
  int tid = threadIdx.x;
  {
    int row = tid >> 2;             // r-idx 0..63
    int col4 = (tid & 3) * 16;      // c-idx base
    const float* sp = s + (size_t)(r0 + row) * C + c0 + col4;
#pragma unroll
    for (int q = 0; q < 16; q++) tile[col4 + q][row] = sp[q];
  }
  __syncthreads();
  int tr8 = (tid & 7) * 8;
#pragma unroll
  for (int i = 0; i < 2; i++) {
    int cc = (tid >> 3) + i * 32;
    ushort tmp[8];
#pragma unroll
    for (int j = 0; j < 8; j++) tmp[j] = f2bf(tile[cc][tr8 + j]);
    *(uint4*)(d + (size_t)(c0 + cc) * R + r0 + tr8) = *(const uint4*)tmp;
  }
}

// ====== fast GEMM1: H(bf16) = relu(gather(xb) @ W1bt^T + b1), m97-style staging ======
__global__ __launch_bounds__(256) void gemm1f_kernel(
    const ushort* __restrict__ xb, const ushort* __restrict__ W1bt,
    const float* __restrict__ b1, const int* __restrict__ rowtok,
    const int* __restrict__ off, ushort* __restrict__ H,
    int chunk_base, int nx)
{
  __shared__ ushort As[128 * 64];
  __shared__ ushort Bs[128 * 64];
  int per = (nx + 7) >> 3;
  int wid = blockIdx.x;
  int rest = wid >> 3;
  int y = rest & 31;                 // ny = 32, y inner for L2 reuse of A-tile
  int bx = (wid & 7) * per + (rest >> 5);
  if (bx >= nx) return;
  int row0 = chunk_base + bx * 128;
  int total = off[E_];
  if (row0 >= total) return;
  int e = 0;
  while (e < E_ - 1 && off[e + 1] <= row0) e++;
  int f0 = y * 128;
  int tid = threadIdx.x;
  int lane = tid & 63;
  int wm = (tid >> 6) & 1, wn = tid >> 7;
  int l15 = lane & 15, quad = lane >> 4;

  const ushort* aptr[4];
  const ushort* bptr[4];
  ushort* aL[4];
  ushort* bL[4];
#pragma unroll
  for (int j = 0; j < 4; j++) {
    int p = j * 256 + tid;
    int row = p >> 3;
    int kcl = (p & 7) ^ (row & 7);   // XOR chunk swizzle
    int tok = rowtok[row0 + row];
    if (tok < 0) tok = 0;            // pad rows: finite garbage, never read
    aptr[j] = xb + (size_t)tok * D_ + kcl * 8;
    bptr[j] = W1bt + ((size_t)e * F_ + f0 + row) * D_ + kcl * 8;
    int cb = j * 256 + (tid & 192);  // wave-uniform chunk base
    aL[j] = As + cb * 8;
    bL[j] = Bs + cb * 8;
  }

  f32x4 acc[4][4];
  f32x4 zz = {0.f, 0.f, 0.f, 0.f};
  for (int i = 0; i < 4; i++) for (int j = 0; j < 4; j++) acc[i][j] = zz;

  for (int k0 = 0; k0 < D_; k0 += 64) {
#pragma unroll
    for (int j = 0; j < 4; j++) gld16(aptr[j] + k0, aL[j]);
#pragma unroll
    for (int j = 0; j < 4; j++) gld16(bptr[j] + k0, bL[j]);
    __syncthreads();
#pragma unroll
    for (int s = 0; s < 2; s++) {
      int cp = (s * 4 + quad) ^ (l15 & 7);
      short8 a[4], b[4];
#pragma unroll
      for (int i = 0; i < 4; i++)
        a[i] = *(const short8*)&As[((wm * 64 + i * 16 + l15) * 8 + cp) * 8];
#pragma unroll
      for (int j = 0; j < 4; j++)
        b[j] = *(const short8*)&Bs[((wn * 64 + j * 16 + l15) * 8 + cp) * 8];
#pragma unroll
      for (int i = 0; i < 4; i++)
#pragma unroll
        for (int j = 0; j < 4; j++)
          acc[i][j] = mfma16(a[i], b[j], acc[i][j]);
    }
    __syncthreads();
  }

  float bv[4];
#pragma unroll
  for (int j = 0; j < 4; j++)
    bv[j] = b1[e * F_ + f0 + wn * 64 + j * 16 + l15];
  ushort* Hb = H + (size_t)(row0 - chunk_base) * F_;
#pragma unroll
  for (int i = 0; i < 4; i++) {
    int mrow = wm * 64 + i * 16 + quad * 4;
#pragma unroll
    for (int rg = 0; rg < 4; rg++) {
      ushort* dst = Hb + (size_t)(mrow + rg) * F_ + f0;
#pragma unroll
      for (int j = 0; j < 4; j++) {
        float vv = acc[i][j][rg] + bv[j];
        vv = vv > 0.f ? vv : 0.f;
        dst[wn * 64 + j * 16 + l15] = f2bf(vv);
      }
    }
  }
}

// ====== fast GEMM2: Ya = H @ W2bt^T, m97-style staging ======
template<bool YF32>
__global__ __launch_bounds__(256) void gemm2f_kernel(
    const ushort* __restrict__ H, const ushort* __restrict__ W2bt,
    const int* __restrict__ off, void* __restrict__ Ya,
    int chunk_base, int nx)
{
  __shared__ ushort As[128 * 64];
  __shared__ ushort Bs[128 * 64];
  int per = (nx + 7) >> 3;
  int wid = blockIdx.x;
  int rest = wid >> 3;
  int y = rest & 7;                  // ny = 8, y inner
  int bx = (wid & 7) * per + (rest >> 3);
  if (bx >= nx) return;
  int row0 = chunk_base + bx * 128;
  int total = off[E_];
  if (row0 >= total) return;
  int e = 0;
  while (e < E_ - 1 && off[e + 1] <= row0) e++;
  int d0 = y * 128;
  int tid = threadIdx.x;
  int lane = tid & 63;
  int wm = (tid >> 6) & 1, wn = tid >> 7;
  int l15 = lane & 15, quad = lane >> 4;

  const ushort* aptr[4];
  const ushort* bptr[4];
  ushort* aL[4];
  ushort* bL[4];
#pragma unroll
  for (int j = 0; j < 4; j++) {
    int p = j * 256 + tid;
    int row = p >> 3;
    int kcl = (p & 7) ^ (row & 7);
    aptr[j] = H + ((size_t)(bx * 128 + row)) * F_ + kcl * 8;
    bptr[j] = W2bt + ((size_t)e * D_ + d0 + row) * F_ + kcl * 8;
    int cb = j * 256 + (tid & 192);
    aL[j] = As + cb * 8;
    bL[j] = Bs + cb * 8;
  }

  f32x4 acc[4][4];
  f32x4 zz = {0.f, 0.f, 0.f, 0.f};
  for (int i = 0; i < 4; i++) for (int j = 0; j < 4; j++) acc[i][j] = zz;

  for (int k0 = 0; k0 < F_; k0 += 64) {
#pragma unroll
    for (int j = 0; j < 4; j++) gld16(aptr[j] + k0, aL[j]);
#pragma unroll
    for (int j = 0; j < 4; j++) gld16(bptr[j] + k0, bL[j]);
    __syncthreads();
#pragma unroll
    for (int s = 0; s < 2; s++) {
      int cp = (s * 4 + quad) ^ (l15 & 7);
      short8 a[4], b[4];
#pragma unroll
      for (int i = 0; i < 4; i++)
        a[i] = *(const short8*)&As[((wm * 64 + i * 16 + l15) * 8 + cp) * 8];
#pragma unroll
      for (int j = 0; j < 4; j++)
        b[j] = *(const short8*)&Bs[((wn * 64 + j * 16 + l15) * 8 + cp) * 8];
#pragma unroll
      for (int i = 0; i < 4; i++)
#pragma unroll
        for (int j = 0; j < 4; j++)
          acc[i][j] = mfma16(a[i], b[j], acc[i][j]);
    }
    __syncthreads();
  }

#pragma unroll
  for (int i = 0; i < 4; i++) {
    int mrow = wm * 64 + i * 16 + quad * 4;
#pragma unroll
    for (int rg = 0; rg < 4; rg++) {
      size_t base = (size_t)(row0 + mrow + rg) * D_ + d0;
#pragma unroll
      for (int j = 0; j < 4; j++) {
        int cc = wn * 64 + j * 16 + l15;
        if (YF32) ((float*)Ya)[base + cc] = acc[i][j][rg];
        else ((ushort*)Ya)[base + cc] = f2bf(acc[i][j][rg]);
      }
    }
  }
}

// ============ fallback GEMMs (validated round-2 code), used only if ws is small ============
template<bool XB, bool BT>
__global__ __launch_bounds__(256) void gemm1_kernel(
    const float* __restrict__ x, const ushort* __restrict__ xb,
    const ushort* __restrict__ W1bt, const float* __restrict__ W1nat,
    const float* __restrict__ b1, const int* __restrict__ rowtok,
    const int* __restrict__ off, ushort* __restrict__ H, int chunk_base)
{
  __shared__ ushort As[128 * 72];
  __shared__ ushort Bs[128 * 72];
  int row0 = chunk_base + blockIdx.x * 128;
  int total = off[E_];
  if (row0 >= total) return;
  int e = 0;
  while (e < E_ - 1 && off[e + 1] <= row0) e++;
  int f0 = blockIdx.y * 128;
  int tid = threadIdx.x;
  int wave = tid >> 6, lane = tid & 63;
  int wm = wave & 1, wn = wave >> 1;
  int l15 = lane & 15, quad = lane >> 4;

  int r = tid >> 1, h = tid & 1;
  int tokA = rowtok[row0 + r];
  size_t aoff = ((tokA >= 0) ? (size_t)tokA * D_ : 0) + h * 32;

  f32x4 acc[4][4];
  f32x4 zz = {0.f, 0.f, 0.f, 0.f};
  for (int i = 0; i < 4; i++) for (int j = 0; j < 4; j++) acc[i][j] = zz;

  for (int k0 = 0; k0 < D_; k0 += 64) {
    for (int q = 0; q < 4; q++) {
      uint4 v;
      if (tokA >= 0) {
        if (XB) {
          v = *(const uint4*)(xb + aoff + k0 + q * 8);
        } else {
          float4 fa = *(const float4*)(x + aoff + k0 + q * 8);
          float4 fb = *(const float4*)(x + aoff + k0 + q * 8 + 4);
          ushort t8[8] = {f2bf(fa.x), f2bf(fa.y), f2bf(fa.z), f2bf(fa.w),
                          f2bf(fb.x), f2bf(fb.y), f2bf(fb.z), f2bf(fb.w)};
          v = *(const uint4*)t8;
        }
      } else v = make_uint4(0u, 0u, 0u, 0u);
      *(uint4*)&As[r * 72 + h * 32 + q * 8] = v;
    }
    if (BT) {
      const ushort* bs = W1bt + ((size_t)e * F_ + f0 + r) * D_ + k0 + h * 32;
      for (int q = 0; q < 4; q++)
        *(uint4*)&Bs[r * 72 + h * 32 + q * 8] = *(const uint4*)(bs + q * 8);
    } else {
      for (int i = 0; i < 8; i++) {
        int c = tid + i * 256;
        int kk = c >> 5;
        int n4 = (c & 31) * 4;
        float4 v = *(const float4*)(W1nat + (size_t)e * D_ * F_ +
                                    (size_t)(k0 + kk) * F_ + f0 + n4);
        Bs[(n4 + 0) * 72 + kk] = f2bf(v.x);
        Bs[(n4 + 1) * 72 + kk] = f2bf(v.y);
        Bs[(n4 + 2) * 72 + kk] = f2bf(v.z);
        Bs[(n4 + 3) * 72 + kk] = f2bf(v.w);
      }
    }
    __syncthreads();
    for (int s = 0; s < 2; s++) {
      int kc = s * 32 + quad * 8;
      short8 a[4], b[4];
      for (int i = 0; i < 4; i++)
        a[i] = *(const short8*)&As[(wm * 64 + i * 16 + l15) * 72 + kc];
      for (int j = 0; j < 4; j++)
        b[j] = *(const short8*)&Bs[(wn * 64 + j * 16 + l15) * 72 + kc];
      for (int i = 0; i < 4; i++)
        for (int j = 0; j < 4; j++)
          acc[i][j] = mfma16(a[i], b[j], acc[i][j]);
    }
    __syncthreads();
  }

  float bv[4];
  for (int j = 0; j < 4; j++)
    bv[j] = b1[e * F_ + f0 + wn * 64 + j * 16 + l15];
  ushort* Hb = H + (size_t)(row0 - chunk_base) * F_;
  for (int i = 0; i < 4; i++) {
    int mrow = wm * 64 + i * 16 + quad * 4;
    for (int rg = 0; rg < 4; rg++) {
      ushort* dst = Hb + (size_t)(mrow + rg) * F_ + f0;
      for (int j = 0; j < 4; j++) {
        float vv = acc[i][j][rg] + bv[j];
        vv = vv > 0.f ? vv : 0.f;
        dst[wn * 64 + j * 16 + l15] = f2bf(vv);
      }
    }
  }
}

template<bool YF32>
__global__ __launch_bounds__(256) void gemm2_kernel(
    const ushort* __restrict__ H, const float* __restrict__ W2nat,
    const int* __restrict__ off, void* __restrict__ Ya, int chunk_base)
{
  __shared__ ushort As[128 * 72];
  __shared__ ushort Bs[128 * 72];
  int row0 = chunk_base + blockIdx.x * 128;
  int total = off[E_];
  if (row0 >= total) return;
  int e = 0;
  while (e < E_ - 1 && off[e + 1] <= row0) e++;
  int d0 = blockIdx.y * 128;
  int tid = threadIdx.x;
  int wave = tid >> 6, lane = tid & 63;
  int wm = wave & 1, wn = wave >> 1;
  int l15 = lane & 15, quad = lane >> 4;

  int r = tid >> 1, h = tid & 1;
  const ushort* aSrc = H + (size_t)(blockIdx.x * 128 + r) * F_ + h * 32;

  f32x4 acc[4][4];
  f32x4 zz = {0.f, 0.f, 0.f, 0.f};
  for (int i = 0; i < 4; i++) for (int j = 0; j < 4; j++) acc[i][j] = zz;

  for (int k0 = 0; k0 < F_; k0 += 64) {
    for (int q = 0; q < 4; q++)
      *(uint4*)&As[r * 72 + h * 32 + q * 8] = *(const uint4*)(aSrc + k0 + q * 8);
    for (int i = 0; i < 8; i++) {
      int c = tid + i * 256;
      int kk = c >> 5;
      int n4 = (c & 31) * 4;
      float4 v = *(const float4*)(W2nat + (size_t)e * F_ * D_ +
                                  (size_t)(k0 + kk) * D_ + d0 + n4);
      Bs[(n4 + 0) * 72 + kk] = f2bf(v.x);
      Bs[(n4 + 1) * 72 + kk] = f2bf(v.y);
      Bs[(n4 + 2) * 72 + kk] = f2bf(v.z);
      Bs[(n4 + 3) * 72 + kk] = f2bf(v.w);
    }
    __syncthreads();
    for (int s = 0; s < 2; s++) {
      int kc = s * 32 + quad * 8;
      short8 a[4], b[4];
      for (int i = 0; i < 4; i++)
        a[i] = *(const short8*)&As[(wm * 64 + i * 16 + l15) * 72 + kc];
      for (int j = 0; j < 4; j++)
        b[j] = *(const short8*)&Bs[(wn * 64 + j * 16 + l15) * 72 + kc];
      for (int i = 0; i < 4; i++)
        for (int j = 0; j < 4; j++)
          acc[i][j] = mfma16(a[i], b[j], acc[i][j]);
    }
    __syncthreads();
  }

  for (int i = 0; i < 4; i++) {
    int mrow = wm * 64 + i * 16 + quad * 4;
    for (int rg = 0; rg < 4; rg++) {
      size_t base = (size_t)(row0 + mrow + rg) * D_ + d0;
      for (int j = 0; j < 4; j++) {
        int cc = wn * 64 + j * 16 + l15;
        if (YF32) ((float*)Ya)[base + cc] = acc[i][j][rg];
        else ((ushort*)Ya)[base + cc] = f2bf(acc[i][j][rg]);
      }
    }
  }
}

// -------- combine: y[t] = w0*(Ya[p0]+b2[e0]) + w1*(Ya[p1]+b2[e1]) --------
template<bool YF32>
__global__ __launch_bounds__(256) void combine_kernel(
    const void* __restrict__ Ya, const float* __restrict__ b2,
    const int* __restrict__ tpos, const int* __restrict__ tke,
    const float* __restrict__ tkw, float* __restrict__ y)
{
  int t = blockIdx.x;
  int c = threadIdx.x * 4;
  int p0 = tpos[2 * t], p1 = tpos[2 * t + 1];
  int e0 = tke[2 * t], e1 = tke[2 * t + 1];
  float w0 = tkw[2 * t], w1 = tkw[2 * t + 1];
  float a0[4], a1[4];
  if (YF32) {
    float4 va = *(const float4*)((const float*)Ya + (size_t)p0 * D_ + c);
    float4 vb = *(const float4*)((const float*)Ya + (size_t)p1 * D_ + c);
    a0[0] = va.x; a0[1] = va.y; a0[2] = va.z; a0[3] = va.w;
    a1[0] = vb.x; a1[1] = vb.y; a1[2] = vb.z; a1[3] = vb.w;
  } else {
    uint2 ua = *(const uint2*)((const ushort*)Ya + (size_t)p0 * D_ + c);
    uint2 ub = *(const uint2*)((const ushort*)Ya + (size_t)p1 * D_ + c);
    const ushort* pa = (const ushort*)&ua;
    const ushort* pb = (const ushort*)&ub;
    for (int q = 0; q < 4; q++) {
      a0[q] = __uint_as_float(((uint32_t)pa[q]) << 16);
      a1[q] = __uint_as_float(((uint32_t)pb[q]) << 16);
    }
  }
  float4 vb0 = *(const float4*)(b2 + (size_t)e0 * D_ + c);
  float4 vb1 = *(const float4*)(b2 + (size_t)e1 * D_ + c);
  float4 o;
  o.x = w0 * (a0[0] + vb0.x) + w1 * (a1[0] + vb1.x);
  o.y = w0 * (a0[1] + vb0.y) + w1 * (a1[1] + vb1.y);
  o.z = w0 * (a0[2] + vb0.z) + w1 * (a1[2] + vb1.z);
  o.w = w0 * (a0[3] + vb0.w) + w1 * (a1[3] + vb1.w);
  *(float4*)(y + (size_t)t * D_ + c) = o;
}

extern "C" void kernel_launch(void* const* d_in, const int* in_sizes, int n_in,
                              void* d_out, int out_size, void* d_ws, size_t ws_size,
                              hipStream_t stream) {
  (void)in_sizes; (void)n_in; (void)out_size;
  const float* x  = (const float*)d_in[0];
  const float* Wr = (const float*)d_in[1];
  const float* W1 = (const float*)d_in[2];
  const float* b1 = (const float*)d_in[3];
  const float* W2 = (const float*)d_in[4];
  const float* b2 = (const float*)d_in[5];
  float* out = (float*)d_out;

  char* ws = (char*)d_ws;
  int*   cnt    = (int*)(ws + 0);
  int*   fill   = (int*)(ws + 32);
  float* imp    = (float*)(ws + 64);
  float* z2     = (float*)(ws + 96);
  int*   off    = (int*)(ws + 128);
  int*   tke    = (int*)(ws + 256);
  float* tkw    = (float*)(ws + 256 + 65536);
  int*   tpos   = (int*)(ws + 256 + 2 * 65536);
  int*   rowtok = (int*)(ws + 256 + 3 * 65536);
  size_t p = 256 + 3 * 65536 + (size_t)CAP * 4;
  p = (p + 4095) & ~(size_t)4095;

  const size_t XB_SZ = (size_t)NTOK * D_ * 2;          // 16.8 MB
  const size_t YA32  = (size_t)CAP * D_ * 4;           // 71.3 MB
  const size_t YA16  = (size_t)CAP * D_ * 2;           // 35.7 MB
  const size_t WT    = (size_t)E_ * D_ * F_ * 2;       // 67.1 MB
  const size_t HROW  = (size_t)F_ * 2;
  const size_t MINH  = 128 * HROW;                     // 1 MB

  bool xb_on = true, ya32 = true;
  if (ws_size < p + XB_SZ + YA32 + MINH) {
    ya32 = false;
    if (ws_size < p + XB_SZ + YA16 + MINH) xb_on = false;
  }
  ushort* xb = nullptr;
  if (xb_on) { xb = (ushort*)(ws + p); p += XB_SZ; }
  void* Ya = (void*)(ws + p);
  p += ya32 ? YA32 : YA16;

  bool w1t_on = false, w2t_on = false;
  ushort* W1bt = nullptr; ushort* W2bt = nullptr;
  if (ws_size >= p + WT + MINH) { w1t_on = true; W1bt = (ushort*)(ws + p); p += WT; }
  if (ws_size >= p + WT + MINH) { w2t_on = true; W2bt = (ushort*)(ws + p); p += WT; }

  size_t hav = ws_size > p ? ws_size - p : 0;
  long long chl = (long long)(hav / HROW);
  int CH = (int)(chl & ~127LL);
  if (CH < 128) CH = 128;
  if (CH > CAP) CH = CAP;
  ushort* Hbuf = (ushort*)(ws + p);
  int nchunks = (CAP + CH - 1) / CH;

  hipMemsetAsync(ws, 0, 128, stream);
  hipMemsetAsync(rowtok, 0xFF, (size_t)CAP * 4, stream);
  router_kernel<<<NTOK / 4, 256, 0, stream>>>(x, Wr, cnt, imp, z2, tke, tkw, xb);
  finalize_kernel<<<1, 64, 0, stream>>>(cnt, imp, z2, off, out + (size_t)NTOK * D_);
  scatter_kernel<<<NTOK / 256, 256, 0, stream>>>(tke, off, fill, rowtok, tpos);
  if (w1t_on)
    transpose_cast_kernel<<<dim3(F_ / 64, D_ / 64, E_), 256, 0, stream>>>(W1, W1bt, D_, F_);
  if (w2t_on)
    transpose_cast_kernel<<<dim3(D_ / 64, F_ / 64, E_), 256, 0, stream>>>(W2, W2bt, F_, D_);

  for (int c = 0; c < nchunks; c++) {
    int cb = c * CH;
    int nx = CH / 128;
    int per = (nx + 7) >> 3;
    if (xb_on && w1t_on) {
      gemm1f_kernel<<<8 * per * 32, 256, 0, stream>>>(xb, W1bt, b1, rowtok, off, Hbuf, cb, nx);
    } else {
      dim3 g1(nx, F_ / 128);
      if (xb_on) gemm1_kernel<true, false><<<g1, 256, 0, stream>>>(x, xb, W1bt, W1, b1, rowtok, off, Hbuf, cb);
      else       gemm1_kernel<false, false><<<g1, 256, 0, stream>>>(x, xb, W1bt, W1, b1, rowtok, off, Hbuf, cb);
    }
    if (w2t_on) {
      if (ya32) gemm2f_kernel<true><<<8 * per * 8, 256, 0, stream>>>(Hbuf, W2bt, off, Ya, cb, nx);
      else      gemm2f_kernel<false><<<8 * per * 8, 256, 0, stream>>>(Hbuf, W2bt, off, Ya, cb, nx);
    } else {
      dim3 g2(nx, D_ / 128);
      if (ya32) gemm2_kernel<true><<<g2, 256, 0, stream>>>(Hbuf, W2, off, Ya, cb);
      else      gemm2_kernel<false><<<g2, 256, 0, stream>>>(Hbuf, W2, off, Ya, cb);
    }
  }
  if (ya32) combine_kernel<true><<<NTOK, 256, 0, stream>>>(Ya, b2, tpos, tke, tkw, out);
  else      combine_kernel<false><<<NTOK, 256, 0, stream>>>(Ya, b2, tpos, tke, tkw, out);
}

// Round 4
// 816.524 us; speedup vs baseline: 1.2078x; 1.0693x over previous
//
#include <hip/hip_runtime.h>
#include <stdint.h>

#define E_ 8
#define D_ 1024
#define F_ 4096
#define NTOK 8192
#define NASSIGN 16384
#define CAP 17408   // 16384 + 8*128 worst-case padding, multiple of 128

typedef __attribute__((ext_vector_type(8))) short short8;
typedef __attribute__((ext_vector_type(8))) __bf16 bf16x8;
typedef __attribute__((ext_vector_type(4))) float f32x4;

__device__ __forceinline__ ushort f2bf(float f) {
  uint32_t u = __float_as_uint(f);
  uint32_t r = (u + 0x7fffu + ((u >> 16) & 1u)) >> 16;
  return (ushort)r;
}

__device__ __forceinline__ f32x4 mfma16(short8 a, short8 b, f32x4 c) {
  return __builtin_amdgcn_mfma_f32_16x16x32_bf16(
      __builtin_bit_cast(bf16x8, a), __builtin_bit_cast(bf16x8, b), c, 0, 0, 0);
}

// async global->LDS, 16B per lane. LDS dest is wave-uniform base + lane*16.
__device__ __forceinline__ void gld16(const ushort* g, ushort* l) {
  __builtin_amdgcn_global_load_lds(
      (const __attribute__((address_space(1))) unsigned int*)(const void*)g,
      (__attribute__((address_space(3))) unsigned int*)(void*)l, 16, 0, 0);
}

// one BK=32 compute step: 8 ds_read_b128 + 16 MFMA per wave.
// LDS layout: row-major 128 rows x 4 chunks of 8 ushorts, chunk xor (row&3).
__device__ __forceinline__ void kstep(const ushort* A, const ushort* B,
                                      int wm, int wn, int l15, int quad,
                                      f32x4 (&acc)[4][4]) {
  short8 a[4], b[4];
#pragma unroll
  for (int i = 0; i < 4; i++) {
    int row = wm * 64 + i * 16 + l15;
    int ph = quad ^ (row & 3);
    a[i] = *(const short8*)&A[(row * 4 + ph) * 8];
  }
#pragma unroll
  for (int j = 0; j < 4; j++) {
    int row = wn * 64 + j * 16 + l15;
    int ph = quad ^ (row & 3);
    b[j] = *(const short8*)&B[(row * 4 + ph) * 8];
  }
#pragma unroll
  for (int i = 0; i < 4; i++)
#pragma unroll
    for (int j = 0; j < 4; j++)
      acc[i][j] = mfma16(a[i], b[j], acc[i][j]);
}

// ---------------- router: one wave per token, all fp32; fused x->bf16 cast ----------------
__global__ __launch_bounds__(256) void router_kernel(
    const float* __restrict__ x, const float* __restrict__ Wr,
    int* __restrict__ cnt, float* __restrict__ imp, float* __restrict__ z2,
    int* __restrict__ tke, float* __restrict__ tkw, ushort* __restrict__ xb)
{
  __shared__ float sWr[E_ * D_];
  __shared__ float bImp[E_];
  __shared__ float bZ2;
  __shared__ int bCnt[E_];
  int tid = threadIdx.x;
  for (int i = 0; i < 4; i++) {
    int d = tid + i * 256;
    float4 v0 = *(const float4*)(Wr + (size_t)d * E_);
    float4 v1 = *(const float4*)(Wr + (size_t)d * E_ + 4);
    sWr[0 * D_ + d] = v0.x; sWr[1 * D_ + d] = v0.y;
    sWr[2 * D_ + d] = v0.z; sWr[3 * D_ + d] = v0.w;
    sWr[4 * D_ + d] = v1.x; sWr[5 * D_ + d] = v1.y;
    sWr[6 * D_ + d] = v1.z; sWr[7 * D_ + d] = v1.w;
  }
  if (tid < E_) { bImp[tid] = 0.f; bCnt[tid] = 0; }
  if (tid == E_) bZ2 = 0.f;
  __syncthreads();

  int wave = tid >> 6, lane = tid & 63;
  int t = blockIdx.x * 4 + wave;
  const float* xr = x + (size_t)t * D_;
  float part[E_];
  for (int e = 0; e < E_; e++) part[e] = 0.f;
  for (int i = 0; i < 4; i++) {
    int d0 = i * 256 + lane * 4;
    float4 xv = *(const float4*)(xr + d0);
    if (xb) {
      ushort o[4] = {f2bf(xv.x), f2bf(xv.y), f2bf(xv.z), f2bf(xv.w)};
      *(uint2*)(xb + (size_t)t * D_ + d0) = *(const uint2*)o;
    }
    for (int e = 0; e < E_; e++)
      part[e] += xv.x * sWr[e * D_ + d0] + xv.y * sWr[e * D_ + d0 + 1] +
                 xv.z * sWr[e * D_ + d0 + 2] + xv.w * sWr[e * D_ + d0 + 3];
  }
  for (int sh = 32; sh >= 1; sh >>= 1)
    for (int e = 0; e < E_; e++)
      part[e] += __shfl_xor(part[e], sh, 64);

  // top-2, JAX tie semantics (first index wins)
  float v1 = part[0]; int i1 = 0;
  for (int e = 1; e < E_; e++) if (part[e] > v1) { v1 = part[e]; i1 = e; }
  float v2 = -3.4e38f; int i2 = 0;
  for (int e = 0; e < E_; e++) if (e != i1 && part[e] > v2) { v2 = part[e]; i2 = e; }
  float w1f = 1.f / (1.f + __expf(v2 - v1));
  float w2f = 1.f - w1f;

  float s = 0.f;
  float pr[E_];
  for (int e = 0; e < E_; e++) { float ex = __expf(part[e] - v1); pr[e] = ex; s += ex; }
  float inv = 1.f / s;
  float z = v1 + __logf(s);

  if (lane == 0) {
    tke[2 * t] = i1; tke[2 * t + 1] = i2;
    tkw[2 * t] = w1f; tkw[2 * t + 1] = w2f;
    for (int e = 0; e < E_; e++) atomicAdd(&bImp[e], pr[e] * inv);
    atomicAdd(&bZ2, z * z);
    atomicAdd(&bCnt[i1], 1);
    atomicAdd(&bCnt[i2], 1);
  }
  __syncthreads();
  if (tid < E_) { atomicAdd(&imp[tid], bImp[tid]); atomicAdd(&cnt[tid], bCnt[tid]); }
  if (tid == E_) atomicAdd(z2, bZ2);
}

// ---------------- finalize: offsets + tail outputs (all fp32) ----------------
__global__ void finalize_kernel(const int* __restrict__ cnt, const float* __restrict__ imp,
                                const float* __restrict__ z2, int* __restrict__ off,
                                float* __restrict__ tail)
{
  if (threadIdx.x == 0 && blockIdx.x == 0) {
    int o = 0;
    for (int e = 0; e < E_; e++) { off[e] = o; o += ((cnt[e] + 127) & ~127); }
    off[E_] = o;
    for (int e = 0; e < E_; e++) tail[e] = (float)cnt[e];
    for (int e = 0; e < E_; e++) tail[E_ + e] = (float)cnt[e] / (float)NASSIGN;
    float sum2 = 0.f;
    for (int e = 0; e < E_; e++) { float p = imp[e] / (float)NTOK; sum2 += p * p; }
    float lb = 8.f * sum2 * 0.01f;
    float zl = (z2[0] / (float)NTOK) * 0.001f;
    tail[2 * E_] = lb + zl;
  }
}

// ------- scatter with LDS aggregation: 256 global atomics instead of 16384 -------
__global__ __launch_bounds__(256) void scatter_kernel(
    const int* __restrict__ tke, const int* __restrict__ off, int* __restrict__ fill,
    int* __restrict__ rowtok, int* __restrict__ tpos)
{
  __shared__ int lcnt[E_], lbase[E_];
  int tid = threadIdx.x;
  if (tid < E_) lcnt[tid] = 0;
  __syncthreads();
  int t = blockIdx.x * 256 + tid;
  int e0 = tke[2 * t], e1 = tke[2 * t + 1];
  int r0 = atomicAdd(&lcnt[e0], 1);
  int r1 = atomicAdd(&lcnt[e1], 1);
  __syncthreads();
  if (tid < E_) lbase[tid] = atomicAdd(&fill[tid], lcnt[tid]);
  __syncthreads();
  int p0 = off[e0] + lbase[e0] + r0;
  int p1 = off[e1] + lbase[e1] + r1;
  rowtok[p0] = t; rowtok[p1] = t;
  tpos[2 * t] = p0; tpos[2 * t + 1] = p1;
}

// ------- transpose+cast: dst(bf16)[z][c][r] = src(fp32)[z][r][c]; tile is [c][r] -------
__global__ __launch_bounds__(256) void transpose_cast_kernel(
    const float* __restrict__ src, ushort* __restrict__ dst, int R, int C)
{
  __shared__ float tile[64][68];   // [c-idx][r-idx], ld=68 (+4 pad)
  const float* s = src + (size_t)blockIdx.z * R * C;
  ushort* d = dst + (size_t)blockIdx.z * R * C;
  int c0 = blockIdx.x * 64, r0 = blockIdx.y * 64;
  int tid = threadIdx.x;
  {
    int row = tid >> 2;             // r-idx 0..63
    int col4 = (tid & 3) * 16;      // c-idx base
    const float* sp = s + (size_t)(r0 + row) * C + c0 + col4;
#pragma unroll
    for (int q = 0; q < 16; q++) tile[col4 + q][row] = sp[q];
  }
  __syncthreads();
  int tr8 = (tid & 7) * 8;
#pragma unroll
  for (int i = 0; i < 2; i++) {
    int cc = (tid >> 3) + i * 32;
    ushort tmp[8];
#pragma unroll
    for (int j = 0; j < 8; j++) tmp[j] = f2bf(tile[cc][tr8 + j]);
    *(uint4*)(d + (size_t)(c0 + cc) * R + r0 + tr8) = *(const uint4*)tmp;
  }
}

// ====== fast GEMM1: H(bf16) = relu(gather(xb) @ W1bt^T + b1) ======
// BK=32, LDS double-buffered, prefetch(k+1) -> compute(k) -> barrier.
__global__ __launch_bounds__(256) void gemm1f_kernel(
    const ushort* __restrict__ xb, const ushort* __restrict__ W1bt,
    const float* __restrict__ b1, const int* __restrict__ rowtok,
    const int* __restrict__ off, ushort* __restrict__ H,
    int chunk_base, int nx)
{
  __shared__ ushort lds[16384];    // As0 | As1 | Bs0 | Bs1, each 128*32
  ushort* As0 = lds;
  ushort* As1 = lds + 4096;
  ushort* Bs0 = lds + 8192;
  ushort* Bs1 = lds + 12288;

  int per = (nx + 7) >> 3;
  int wid = blockIdx.x;
  int rest = wid >> 3;
  int y = rest & 31;                 // ny = 32, y inner for L2 reuse of A-tile
  int bx = (wid & 7) * per + (rest >> 5);
  if (bx >= nx) return;
  int row0 = chunk_base + bx * 128;
  int total = off[E_];
  if (row0 >= total) return;
  int e = 0;
  while (e < E_ - 1 && off[e + 1] <= row0) e++;
  int f0 = y * 128;
  int tid = threadIdx.x;
  int lane = tid & 63;
  int wm = (tid >> 6) & 1, wn = tid >> 7;
  int l15 = lane & 15, quad = lane >> 4;

  const ushort* aptr[2];
  const ushort* bptr[2];
  int lu[2];
#pragma unroll
  for (int j = 0; j < 2; j++) {
    int p = j * 256 + tid;
    int row = p >> 2;                // 4 chunks per row
    int kc = (p & 3) ^ (row & 3);    // XOR chunk swizzle (applied to global addr)
    int tok = rowtok[row0 + row];
    if (tok < 0) tok = 0;            // pad rows: finite garbage, never read
    aptr[j] = xb + (size_t)tok * D_ + kc * 8;
    bptr[j] = W1bt + ((size_t)e * F_ + f0 + row) * D_ + kc * 8;
    lu[j] = (j * 256 + (tid & 192)) * 8;   // wave-uniform LDS unit base
  }

  f32x4 acc[4][4];
  f32x4 zz = {0.f, 0.f, 0.f, 0.f};
  for (int i = 0; i < 4; i++) for (int j = 0; j < 4; j++) acc[i][j] = zz;

  const int NK = D_ / 32;   // 32
  // prologue: stage k=0 into buf0
#pragma unroll
  for (int j = 0; j < 2; j++) gld16(aptr[j], As0 + lu[j]);
#pragma unroll
  for (int j = 0; j < 2; j++) gld16(bptr[j], Bs0 + lu[j]);
  __syncthreads();

#pragma unroll 1
  for (int k = 0; k < NK; k += 2) {
    {   // even: prefetch k+1 -> buf1 (always valid), compute buf0
      int ko = (k + 1) * 32;
#pragma unroll
      for (int j = 0; j < 2; j++) gld16(aptr[j] + ko, As1 + lu[j]);
#pragma unroll
      for (int j = 0; j < 2; j++) gld16(bptr[j] + ko, Bs1 + lu[j]);
      kstep(As0, Bs0, wm, wn, l15, quad, acc);
      __syncthreads();
    }
    {   // odd: prefetch k+2 -> buf0 (if valid), compute buf1
      if (k + 2 < NK) {
        int ko = (k + 2) * 32;
#pragma unroll
        for (int j = 0; j < 2; j++) gld16(aptr[j] + ko, As0 + lu[j]);
#pragma unroll
        for (int j = 0; j < 2; j++) gld16(bptr[j] + ko, Bs0 + lu[j]);
      }
      kstep(As1, Bs1, wm, wn, l15, quad, acc);
      __syncthreads();
    }
  }

  // epilogue: bias+relu, repack via LDS, vectorized row stores
  float bv[4];
#pragma unroll
  for (int j = 0; j < 4; j++)
    bv[j] = b1[e * F_ + f0 + wn * 64 + j * 16 + l15];
#pragma unroll
  for (int i = 0; i < 4; i++) {
#pragma unroll
    for (int rg = 0; rg < 4; rg++) {
      int row = wm * 64 + i * 16 + quad * 4 + rg;
#pragma unroll
      for (int j = 0; j < 4; j++) {
        float vv = acc[i][j][rg] + bv[j];
        vv = vv > 0.f ? vv : 0.f;
        lds[row * 128 + wn * 64 + j * 16 + l15] = f2bf(vv);
      }
    }
  }
  __syncthreads();
  {
    int row = tid >> 1, half = tid & 1;
    const ushort* src = lds + row * 128 + half * 64;
    ushort* dst = H + (size_t)(row0 - chunk_base + row) * F_ + f0 + half * 64;
#pragma unroll
    for (int q = 0; q < 8; q++)
      *(uint4*)(dst + q * 8) = *(const uint4*)(src + q * 8);
  }
}

// ====== fast GEMM2: Ya(fp32) = H @ W2bt^T ======
template<bool YF32>
__global__ __launch_bounds__(256) void gemm2f_kernel(
    const ushort* __restrict__ H, const ushort* __restrict__ W2bt,
    const int* __restrict__ off, void* __restrict__ Ya,
    int chunk_base, int nx)
{
  __shared__ ushort lds[16384];
  ushort* As0 = lds;
  ushort* As1 = lds + 4096;
  ushort* Bs0 = lds + 8192;
  ushort* Bs1 = lds + 12288;

  int per = (nx + 7) >> 3;
  int wid = blockIdx.x;
  int rest = wid >> 3;
  int y = rest & 7;                  // ny = 8, y inner
  int bx = (wid & 7) * per + (rest >> 3);
  if (bx >= nx) return;
  int row0 = chunk_base + bx * 128;
  int total = off[E_];
  if (row0 >= total) return;
  int e = 0;
  while (e < E_ - 1 && off[e + 1] <= row0) e++;
  int d0 = y * 128;
  int tid = threadIdx.x;
  int lane = tid & 63;
  int wm = (tid >> 6) & 1, wn = tid >> 7;
  int l15 = lane & 15, quad = lane >> 4;

  const ushort* aptr[2];
  const ushort* bptr[2];
  int lu[2];
#pragma unroll
  for (int j = 0; j < 2; j++) {
    int p = j * 256 + tid;
    int row = p >> 2;
    int kc = (p & 3) ^ (row & 3);
    aptr[j] = H + (size_t)(bx * 128 + row) * F_ + kc * 8;
    bptr[j] = W2bt + ((size_t)e * D_ + d0 + row) * F_ + kc * 8;
    lu[j] = (j * 256 + (tid & 192)) * 8;
  }

  f32x4 acc[4][4];
  f32x4 zz = {0.f, 0.f, 0.f, 0.f};
  for (int i = 0; i < 4; i++) for (int j = 0; j < 4; j++) acc[i][j] = zz;

  const int NK = F_ / 32;   // 128
#pragma unroll
  for (int j = 0; j < 2; j++) gld16(aptr[j], As0 + lu[j]);
#pragma unroll
  for (int j = 0; j < 2; j++) gld16(bptr[j], Bs0 + lu[j]);
  __syncthreads();

#pragma unroll 1
  for (int k = 0; k < NK; k += 2) {
    {
      int ko = (k + 1) * 32;
#pragma unroll
      for (int j = 0; j < 2; j++) gld16(aptr[j] + ko, As1 + lu[j]);
#pragma unroll
      for (int j = 0; j < 2; j++) gld16(bptr[j] + ko, Bs1 + lu[j]);
      kstep(As0, Bs0, wm, wn, l15, quad, acc);
      __syncthreads();
    }
    {
      if (k + 2 < NK) {
        int ko = (k + 2) * 32;
#pragma unroll
        for (int j = 0; j < 2; j++) gld16(aptr[j] + ko, As0 + lu[j]);
#pragma unroll
        for (int j = 0; j < 2; j++) gld16(bptr[j] + ko, Bs0 + lu[j]);
      }
      kstep(As1, Bs1, wm, wn, l15, quad, acc);
      __syncthreads();
    }
  }

#pragma unroll
  for (int i = 0; i < 4; i++) {
    int mrow = wm * 64 + i * 16 + quad * 4;
#pragma unroll
    for (int rg = 0; rg < 4; rg++) {
      size_t base = (size_t)(row0 + mrow + rg) * D_ + d0;
#pragma unroll
      for (int j = 0; j < 4; j++) {
        int cc = wn * 64 + j * 16 + l15;
        if (YF32) ((float*)Ya)[base + cc] = acc[i][j][rg];
        else ((ushort*)Ya)[base + cc] = f2bf(acc[i][j][rg]);
      }
    }
  }
}

// ============ fallback GEMMs (validated round-2 code), used only if ws is small ============
template<bool XB, bool BT>
__global__ __launch_bounds__(256) void gemm1_kernel(
    const float* __restrict__ x, const ushort* __restrict__ xb,
    const ushort* __restrict__ W1bt, const float* __restrict__ W1nat,
    const float* __restrict__ b1, const int* __restrict__ rowtok,
    const int* __restrict__ off, ushort* __restrict__ H, int chunk_base)
{
  __shared__ ushort As[128 * 72];
  __shared__ ushort Bs[128 * 72];
  int row0 = chunk_base + blockIdx.x * 128;
  int total = off[E_];
  if (row0 >= total) return;
  int e = 0;
  while (e < E_ - 1 && off[e + 1] <= row0) e++;
  int f0 = blockIdx.y * 128;
  int tid = threadIdx.x;
  int wave = tid >> 6, lane = tid & 63;
  int wm = wave & 1, wn = wave >> 1;
  int l15 = lane & 15, quad = lane >> 4;

  int r = tid >> 1, h = tid & 1;
  int tokA = rowtok[row0 + r];
  size_t aoff = ((tokA >= 0) ? (size_t)tokA * D_ : 0) + h * 32;

  f32x4 acc[4][4];
  f32x4 zz = {0.f, 0.f, 0.f, 0.f};
  for (int i = 0; i < 4; i++) for (int j = 0; j < 4; j++) acc[i][j] = zz;

  for (int k0 = 0; k0 < D_; k0 += 64) {
    for (int q = 0; q < 4; q++) {
      uint4 v;
      if (tokA >= 0) {
        if (XB) {
          v = *(const uint4*)(xb + aoff + k0 + q * 8);
        } else {
          float4 fa = *(const float4*)(x + aoff + k0 + q * 8);
          float4 fb = *(const float4*)(x + aoff + k0 + q * 8 + 4);
          ushort t8[8] = {f2bf(fa.x), f2bf(fa.y), f2bf(fa.z), f2bf(fa.w),
                          f2bf(fb.x), f2bf(fb.y), f2bf(fb.z), f2bf(fb.w)};
          v = *(const uint4*)t8;
        }
      } else v = make_uint4(0u, 0u, 0u, 0u);
      *(uint4*)&As[r * 72 + h * 32 + q * 8] = v;
    }
    if (BT) {
      const ushort* bs = W1bt + ((size_t)e * F_ + f0 + r) * D_ + k0 + h * 32;
      for (int q = 0; q < 4; q++)
        *(uint4*)&Bs[r * 72 + h * 32 + q * 8] = *(const uint4*)(bs + q * 8);
    } else {
      for (int i = 0; i < 8; i++) {
        int c = tid + i * 256;
        int kk = c >> 5;
        int n4 = (c & 31) * 4;
        float4 v = *(const float4*)(W1nat + (size_t)e * D_ * F_ +
                                    (size_t)(k0 + kk) * F_ + f0 + n4);
        Bs[(n4 + 0) * 72 + kk] = f2bf(v.x);
        Bs[(n4 + 1) * 72 + kk] = f2bf(v.y);
        Bs[(n4 + 2) * 72 + kk] = f2bf(v.z);
        Bs[(n4 + 3) * 72 + kk] = f2bf(v.w);
      }
    }
    __syncthreads();
    for (int s = 0; s < 2; s++) {
      int kc = s * 32 + quad * 8;
      short8 a[4], b[4];
      for (int i = 0; i < 4; i++)
        a[i] = *(const short8*)&As[(wm * 64 + i * 16 + l15) * 72 + kc];
      for (int j = 0; j < 4; j++)
        b[j] = *(const short8*)&Bs[(wn * 64 + j * 16 + l15) * 72 + kc];
      for (int i = 0; i < 4; i++)
        for (int j = 0; j < 4; j++)
          acc[i][j] = mfma16(a[i], b[j], acc[i][j]);
    }
    __syncthreads();
  }

  float bv[4];
  for (int j = 0; j < 4; j++)
    bv[j] = b1[e * F_ + f0 + wn * 64 + j * 16 + l15];
  ushort* Hb = H + (size_t)(row0 - chunk_base) * F_;
  for (int i = 0; i < 4; i++) {
    int mrow = wm * 64 + i * 16 + quad * 4;
    for (int rg = 0; rg < 4; rg++) {
      ushort* dst = Hb + (size_t)(mrow + rg) * F_ + f0;
      for (int j = 0; j < 4; j++) {
        float vv = acc[i][j][rg] + bv[j];
        vv = vv > 0.f ? vv : 0.f;
        dst[wn * 64 + j * 16 + l15] = f2bf(vv);
      }
    }
  }
}

template<bool YF32>
__global__ __launch_bounds__(256) void gemm2_kernel(
    const ushort* __restrict__ H, const float* __restrict__ W2nat,
    const int* __restrict__ off, void* __restrict__ Ya, int chunk_base)
{
  __shared__ ushort As[128 * 72];
  __shared__ ushort Bs[128 * 72];
  int row0 = chunk_base + blockIdx.x * 128;
  int total = off[E_];
  if (row0 >= total) return;
  int e = 0;
  while (e < E_ - 1 && off[e + 1] <= row0) e++;
  int d0 = blockIdx.y * 128;
  int tid = threadIdx.x;
  int wave = tid >> 6, lane = tid & 63;
  int wm = wave & 1, wn = wave >> 1;
  int l15 = lane & 15, quad = lane >> 4;

  int r = tid >> 1, h = tid & 1;
  const ushort* aSrc = H + (size_t)(blockIdx.x * 128 + r) * F_ + h * 32;

  f32x4 acc[4][4];
  f32x4 zz = {0.f, 0.f, 0.f, 0.f};
  for (int i = 0; i < 4; i++) for (int j = 0; j < 4; j++) acc[i][j] = zz;

  for (int k0 = 0; k0 < F_; k0 += 64) {
    for (int q = 0; q < 4; q++)
      *(uint4*)&As[r * 72 + h * 32 + q * 8] = *(const uint4*)(aSrc + k0 + q * 8);
    for (int i = 0; i < 8; i++) {
      int c = tid + i * 256;
      int kk = c >> 5;
      int n4 = (c & 31) * 4;
      float4 v = *(const float4*)(W2nat + (size_t)e * F_ * D_ +
                                  (size_t)(k0 + kk) * D_ + d0 + n4);
      Bs[(n4 + 0) * 72 + kk] = f2bf(v.x);
      Bs[(n4 + 1) * 72 + kk] = f2bf(v.y);
      Bs[(n4 + 2) * 72 + kk] = f2bf(v.z);
      Bs[(n4 + 3) * 72 + kk] = f2bf(v.w);
    }
    __syncthreads();
    for (int s = 0; s < 2; s++) {
      int kc = s * 32 + quad * 8;
      short8 a[4], b[4];
      for (int i = 0; i < 4; i++)
        a[i] = *(const short8*)&As[(wm * 64 + i * 16 + l15) * 72 + kc];
      for (int j = 0; j < 4; j++)
        b[j] = *(const short8*)&Bs[(wn * 64 + j * 16 + l15) * 72 + kc];
      for (int i = 0; i < 4; i++)
        for (int j = 0; j < 4; j++)
          acc[i][j] = mfma16(a[i], b[j], acc[i][j]);
    }
    __syncthreads();
  }

  for (int i = 0; i < 4; i++) {
    int mrow = wm * 64 + i * 16 + quad * 4;
    for (int rg = 0; rg < 4; rg++) {
      size_t base = (size_t)(row0 + mrow + rg) * D_ + d0;
      for (int j = 0; j < 4; j++) {
        int cc = wn * 64 + j * 16 + l15;
        if (YF32) ((float*)Ya)[base + cc] = acc[i][j][rg];
        else ((ushort*)Ya)[base + cc] = f2bf(acc[i][j][rg]);
      }
    }
  }
}

// -------- combine: y[t] = w0*(Ya[p0]+b2[e0]) + w1*(Ya[p1]+b2[e1]) --------
template<bool YF32>
__global__ __launch_bounds__(256) void combine_kernel(
    const void* __restrict__ Ya, const float* __restrict__ b2,
    const int* __restrict__ tpos, const int* __restrict__ tke,
    const float* __restrict__ tkw, float* __restrict__ y)
{
  int t = blockIdx.x;
  int c = threadIdx.x * 4;
  int p0 = tpos[2 * t], p1 = tpos[2 * t + 1];
  int e0 = tke[2 * t], e1 = tke[2 * t + 1];
  float w0 = tkw[2 * t], w1 = tkw[2 * t + 1];
  float a0[4], a1[4];
  if (YF32) {
    float4 va = *(const float4*)((const float*)Ya + (size_t)p0 * D_ + c);
    float4 vb = *(const float4*)((const float*)Ya + (size_t)p1 * D_ + c);
    a0[0] = va.x; a0[1] = va.y; a0[2] = va.z; a0[3] = va.w;
    a1[0] = vb.x; a1[1] = vb.y; a1[2] = vb.z; a1[3] = vb.w;
  } else {
    uint2 ua = *(const uint2*)((const ushort*)Ya + (size_t)p0 * D_ + c);
    uint2 ub = *(const uint2*)((const ushort*)Ya + (size_t)p1 * D_ + c);
    const ushort* pa = (const ushort*)&ua;
    const ushort* pb = (const ushort*)&ub;
    for (int q = 0; q < 4; q++) {
      a0[q] = __uint_as_float(((uint32_t)pa[q]) << 16);
      a1[q] = __uint_as_float(((uint32_t)pb[q]) << 16);
    }
  }
  float4 vb0 = *(const float4*)(b2 + (size_t)e0 * D_ + c);
  float4 vb1 = *(const float4*)(b2 + (size_t)e1 * D_ + c);
  float4 o;
  o.x = w0 * (a0[0] + vb0.x) + w1 * (a1[0] + vb1.x);
  o.y = w0 * (a0[1] + vb0.y) + w1 * (a1[1] + vb1.y);
  o.z = w0 * (a0[2] + vb0.z) + w1 * (a1[2] + vb1.z);
  o.w = w0 * (a0[3] + vb0.w) + w1 * (a1[3] + vb1.w);
  *(float4*)(y + (size_t)t * D_ + c) = o;
}

extern "C" void kernel_launch(void* const* d_in, const int* in_sizes, int n_in,
                              void* d_out, int out_size, void* d_ws, size_t ws_size,
                              hipStream_t stream) {
  (void)in_sizes; (void)n_in; (void)out_size;
  const float* x  = (const float*)d_in[0];
  const float* Wr = (const float*)d_in[1];
  const float* W1 = (const float*)d_in[2];
  const float* b1 = (const float*)d_in[3];
  const float* W2 = (const float*)d_in[4];
  const float* b2 = (const float*)d_in[5];
  float* out = (float*)d_out;

  char* ws = (char*)d_ws;
  int*   cnt    = (int*)(ws + 0);
  int*   fill   = (int*)(ws + 32);
  float* imp    = (float*)(ws + 64);
  float* z2     = (float*)(ws + 96);
  int*   off    = (int*)(ws + 128);
  int*   tke    = (int*)(ws + 256);
  float* tkw    = (float*)(ws + 256 + 65536);
  int*   tpos   = (int*)(ws + 256 + 2 * 65536);
  int*   rowtok = (int*)(ws + 256 + 3 * 65536);
  size_t p = 256 + 3 * 65536 + (size_t)CAP * 4;
  p = (p + 4095) & ~(size_t)4095;

  const size_t XB_SZ = (size_t)NTOK * D_ * 2;          // 16.8 MB
  const size_t YA32  = (size_t)CAP * D_ * 4;           // 71.3 MB
  const size_t YA16  = (size_t)CAP * D_ * 2;           // 35.7 MB
  const size_t WT    = (size_t)E_ * D_ * F_ * 2;       // 67.1 MB
  const size_t HROW  = (size_t)F_ * 2;
  const size_t MINH  = 128 * HROW;                     // 1 MB

  bool xb_on = true, ya32 = true;
  if (ws_size < p + XB_SZ + YA32 + MINH) {
    ya32 = false;
    if (ws_size < p + XB_SZ + YA16 + MINH) xb_on = false;
  }
  ushort* xb = nullptr;
  if (xb_on) { xb = (ushort*)(ws + p); p += XB_SZ; }
  void* Ya = (void*)(ws + p);
  p += ya32 ? YA32 : YA16;

  bool w1t_on = false, w2t_on = false;
  ushort* W1bt = nullptr; ushort* W2bt = nullptr;
  if (ws_size >= p + WT + MINH) { w1t_on = true; W1bt = (ushort*)(ws + p); p += WT; }
  if (ws_size >= p + WT + MINH) { w2t_on = true; W2bt = (ushort*)(ws + p); p += WT; }

  size_t hav = ws_size > p ? ws_size - p : 0;
  long long chl = (long long)(hav / HROW);
  int CH = (int)(chl & ~127LL);
  if (CH < 128) CH = 128;
  if (CH > CAP) CH = CAP;
  ushort* Hbuf = (ushort*)(ws + p);
  int nchunks = (CAP + CH - 1) / CH;

  hipMemsetAsync(ws, 0, 128, stream);
  hipMemsetAsync(rowtok, 0xFF, (size_t)CAP * 4, stream);
  router_kernel<<<NTOK / 4, 256, 0, stream>>>(x, Wr, cnt, imp, z2, tke, tkw, xb);
  finalize_kernel<<<1, 64, 0, stream>>>(cnt, imp, z2, off, out + (size_t)NTOK * D_);
  scatter_kernel<<<NTOK / 256, 256, 0, stream>>>(tke, off, fill, rowtok, tpos);
  if (w1t_on)
    transpose_cast_kernel<<<dim3(F_ / 64, D_ / 64, E_), 256, 0, stream>>>(W1, W1bt, D_, F_);
  if (w2t_on)
    transpose_cast_kernel<<<dim3(D_ / 64, F_ / 64, E_), 256, 0, stream>>>(W2, W2bt, F_, D_);

  for (int c = 0; c < nchunks; c++) {
    int cb = c * CH;
    int nx = CH / 128;
    int per = (nx + 7) >> 3;
    if (xb_on && w1t_on) {
      gemm1f_kernel<<<8 * per * 32, 256, 0, stream>>>(xb, W1bt, b1, rowtok, off, Hbuf, cb, nx);
    } else {
      dim3 g1(nx, F_ / 128);
      if (xb_on) gemm1_kernel<true, false><<<g1, 256, 0, stream>>>(x, xb, W1bt, W1, b1, rowtok, off, Hbuf, cb);
      else       gemm1_kernel<false, false><<<g1, 256, 0, stream>>>(x, xb, W1bt, W1, b1, rowtok, off, Hbuf, cb);
    }
    if (w2t_on) {
      if (ya32) gemm2f_kernel<true><<<8 * per * 8, 256, 0, stream>>>(Hbuf, W2bt, off, Ya, cb, nx);
      else      gemm2f_kernel<false><<<8 * per * 8, 256, 0, stream>>>(Hbuf, W2bt, off, Ya, cb, nx);
    } else {
      dim3 g2(nx, D_ / 128);
      if (ya32) gemm2_kernel<true><<<g2, 256, 0, stream>>>(Hbuf, W2, off, Ya, cb);
      else      gemm2_kernel<false><<<g2, 256, 0, stream>>>(Hbuf, W2, off, Ya, cb);
    }
  }
  if (ya32) combine_kernel<true><<<NTOK, 256, 0, stream>>>(Ya, b2, tpos, tke, tkw, out);
  else      combine_kernel<false><<<NTOK, 256, 0, stream>>>(Ya, b2, tpos, tke, tkw, out);
}